// Round 2
// baseline (6468.555 us; speedup 1.0000x reference)
//
#include <hip/hip_runtime.h>

#define T_STEPS 2048
#define BATCH   64
#define IN_DIM  256
#define HID     512

#define ROWS_REG 384                 // k-rows of w_rec held in VGPRs per thread (192 half2)
#define QREG     (ROWS_REG / 2)      // 192 half2 row-pairs in regs
#define ROWS_LDS (HID - ROWS_REG)    // 128 k-rows in LDS (128 KB slab)
#define QLDS     (ROWS_LDS / 2)      // 64 half2 row-pairs in LDS

typedef _Float16 half_t;
typedef half_t half2_t __attribute__((ext_vector_type(2)));
typedef half_t half8_t __attribute__((ext_vector_type(8)));

#if __has_builtin(__builtin_amdgcn_fdot2)
__device__ __forceinline__ float fdot2(half2_t a, half2_t b, float c) {
    return __builtin_amdgcn_fdot2(a, b, c, false);   // v_dot2_f32_f16
}
#else
__device__ __forceinline__ float fdot2(half2_t a, half2_t b, float c) {
    return c + (float)a.x * (float)b.x + (float)a.y * (float)b.y;
}
#endif

// LDS-only barrier: drains lgkmcnt (LDS) but NOT vmcnt, so per-step global
// h-stores / xp-loads stay in flight across the barrier. Correct because the
// only cross-thread data (hbuf, and parts-free now) lives in LDS.
__device__ __forceinline__ void lds_barrier() {
    asm volatile("s_waitcnt lgkmcnt(0)\n\ts_barrier" ::: "memory");
}

// ---------------------------------------------------------------------------
// K1: x_proj[t*B+b][h] = input[t*B+b][i] @ w_in[i][h]   (unchanged from R1)
// ---------------------------------------------------------------------------
__global__ __launch_bounds__(256, 4)
void xproj_gemm(const float* __restrict__ A, const float* __restrict__ Win,
                float* __restrict__ out) {
    __shared__ float As[32][132];
    __shared__ float Bs[32][132];
    const int tid = threadIdx.x;
    const int m0 = blockIdx.y * 128;
    const int n0 = blockIdx.x * 128;
    const int tm = (tid >> 4) << 3;
    const int tn = (tid & 15) << 3;

    float acc[8][8] = {};

    for (int k0 = 0; k0 < IN_DIM; k0 += 32) {
        {
            const int m  = tid >> 3;
            const int k4 = (tid & 7) << 2;
#pragma unroll
            for (int r = 0; r < 4; ++r) {
                const float4 a4 = *(const float4*)&A[(size_t)(m0 + m + 32 * r) * IN_DIM + k0 + k4];
                As[k4 + 0][m + 32 * r] = a4.x;
                As[k4 + 1][m + 32 * r] = a4.y;
                As[k4 + 2][m + 32 * r] = a4.z;
                As[k4 + 3][m + 32 * r] = a4.w;
            }
        }
        {
            const int kb = tid >> 5;
            const int n4 = (tid & 31) << 2;
#pragma unroll
            for (int r = 0; r < 4; ++r) {
                const float4 b4 = *(const float4*)&Win[(size_t)(k0 + kb + 8 * r) * HID + n0 + n4];
                *(float4*)&Bs[kb + 8 * r][n4] = b4;
            }
        }
        __syncthreads();
#pragma unroll
        for (int kk = 0; kk < 32; ++kk) {
            const float4 a0 = *(const float4*)&As[kk][tm];
            const float4 a1 = *(const float4*)&As[kk][tm + 4];
            const float4 b0 = *(const float4*)&Bs[kk][tn];
            const float4 b1 = *(const float4*)&Bs[kk][tn + 4];
            const float av[8] = {a0.x, a0.y, a0.z, a0.w, a1.x, a1.y, a1.z, a1.w};
            const float bv[8] = {b0.x, b0.y, b0.z, b0.w, b1.x, b1.y, b1.z, b1.w};
#pragma unroll
            for (int i = 0; i < 8; ++i)
#pragma unroll
                for (int j = 0; j < 8; ++j)
                    acc[i][j] = fmaf(av[i], bv[j], acc[i][j]);
        }
        __syncthreads();
    }

#pragma unroll
    for (int i = 0; i < 8; ++i) {
        float4 c0 = {acc[i][0], acc[i][1], acc[i][2], acc[i][3]};
        float4 c1 = {acc[i][4], acc[i][5], acc[i][6], acc[i][7]};
        float* dst = &out[(size_t)(m0 + tm + i) * HID + n0 + tn];
        *(float4*)dst       = c0;
        *(float4*)(dst + 4) = c1;
    }
}

// ---------------------------------------------------------------------------
// K2 v2: one column per thread. 64 WGs x 512 threads.
// Thread j owns output column j: s_j = xp_j + sum_k W[k][j] h[k].
//  - W rows [0,384)  as 192 half2 row-pairs in VGPRs
//  - W rows [384,512) in a 128 KB LDS slab, laid out [qb][col][sub] so the
//    per-step reads are canonical 16B/lane-contiguous ds_read_b128
//  - h double-buffered in LDS as packed half2 (2 x 1 KB); all h reads are
//    wave-uniform broadcast ds_read_b128
//  - no cross-thread reduction; exactly ONE lgkm-only barrier per step
//  - xp(t+1) prefetched before the h(t) store so its vmcnt wait never drains
//    the store (vmcnt retires in order)
// ---------------------------------------------------------------------------
__global__ __launch_bounds__(512, 2)
void rnn_scan(const float* __restrict__ Wrec, float* __restrict__ out) {
    __shared__ alignas(16) half2_t WL[QLDS * HID];   // 64*512 half2 = 128 KB
    __shared__ alignas(16) half2_t hbuf[2][HID / 2]; // 2 x 1 KB

    const int tid = threadIdx.x;
    const int b   = blockIdx.x;
    const int j   = tid;                 // owned column

    // ---- init: W column j -> regs (rows 0..384) + LDS slab (rows 384..512)
    half2_t wreg[QREG];
#pragma unroll
    for (int q = 0; q < QREG; ++q) {
        const float w0 = Wrec[(size_t)(2 * q) * HID + j];
        const float w1 = Wrec[(size_t)(2 * q + 1) * HID + j];
        half2_t w; w.x = (half_t)w0; w.y = (half_t)w1;
        wreg[q] = w;
    }
#pragma unroll
    for (int q = 0; q < QLDS; ++q) {
        const float w0 = Wrec[(size_t)(ROWS_REG + 2 * q) * HID + j];
        const float w1 = Wrec[(size_t)(ROWS_REG + 2 * q + 1) * HID + j];
        half2_t w; w.x = (half_t)w0; w.y = (half_t)w1;
        WL[(q >> 2) * (HID * 4) + j * 4 + (q & 3)] = w;
    }
    ((half_t*)hbuf[0])[j] = (half_t)0.f;   // h0 = 0
    __syncthreads();

    float xpv = out[(size_t)b * HID + j];  // xp for t=0

    for (int t = 0; t < T_STEPS; ++t) {
        const half2_t* hcur = hbuf[t & 1];

        float acc[8] = {};

        // rows [0,384): W from regs, h broadcast from LDS (b128, wave-uniform)
#pragma unroll
        for (int qb = 0; qb < QREG / 4; ++qb) {
            const half8_t hv = *(const half8_t*)&hcur[qb * 4];
            const half2_t h0 = __builtin_shufflevector(hv, hv, 0, 1);
            const half2_t h1 = __builtin_shufflevector(hv, hv, 2, 3);
            const half2_t h2 = __builtin_shufflevector(hv, hv, 4, 5);
            const half2_t h3 = __builtin_shufflevector(hv, hv, 6, 7);
            acc[(4 * qb + 0) & 7] = fdot2(wreg[4 * qb + 0], h0, acc[(4 * qb + 0) & 7]);
            acc[(4 * qb + 1) & 7] = fdot2(wreg[4 * qb + 1], h1, acc[(4 * qb + 1) & 7]);
            acc[(4 * qb + 2) & 7] = fdot2(wreg[4 * qb + 2], h2, acc[(4 * qb + 2) & 7]);
            acc[(4 * qb + 3) & 7] = fdot2(wreg[4 * qb + 3], h3, acc[(4 * qb + 3) & 7]);
        }
        // rows [384,512): W from LDS slab (b128 contiguous), h broadcast
#pragma unroll
        for (int qb = 0; qb < QLDS / 4; ++qb) {
            const half8_t hv = *(const half8_t*)&hcur[QREG + qb * 4];
            const half8_t wv = *(const half8_t*)&WL[qb * (HID * 4) + j * 4];
            acc[(4 * qb + 0) & 7] = fdot2(__builtin_shufflevector(wv, wv, 0, 1),
                                          __builtin_shufflevector(hv, hv, 0, 1), acc[(4 * qb + 0) & 7]);
            acc[(4 * qb + 1) & 7] = fdot2(__builtin_shufflevector(wv, wv, 2, 3),
                                          __builtin_shufflevector(hv, hv, 2, 3), acc[(4 * qb + 1) & 7]);
            acc[(4 * qb + 2) & 7] = fdot2(__builtin_shufflevector(wv, wv, 4, 5),
                                          __builtin_shufflevector(hv, hv, 4, 5), acc[(4 * qb + 2) & 7]);
            acc[(4 * qb + 3) & 7] = fdot2(__builtin_shufflevector(wv, wv, 6, 7),
                                          __builtin_shufflevector(hv, hv, 6, 7), acc[(4 * qb + 3) & 7]);
        }

        // prefetch next xp BEFORE the h store (vmcnt retires in order)
        const int tn = (t + 1 < T_STEPS) ? (t + 1) : (T_STEPS - 1);
        const float xpn = out[((size_t)tn * BATCH + b) * HID + j];

        const float s  = ((acc[0] + acc[1]) + (acc[2] + acc[3])) +
                         ((acc[4] + acc[5]) + (acc[6] + acc[7])) + xpv;
        const float e  = __expf(2.0f * s);
        const float hj = 1.0f - 2.0f / (e + 1.0f);   // tanh(s)

        out[((size_t)t * BATCH + b) * HID + j] = hj;
        if (t == T_STEPS - 1)
            out[(size_t)T_STEPS * BATCH * HID + (size_t)b * HID + j] = hj;

        ((half_t*)hbuf[(t + 1) & 1])[j] = (half_t)hj;
        xpv = xpn;

        lds_barrier();   // lgkm-only: publish new h, keep vmem in flight
    }
}

extern "C" void kernel_launch(void* const* d_in, const int* in_sizes, int n_in,
                              void* d_out, int out_size, void* d_ws, size_t ws_size,
                              hipStream_t stream) {
    const float* A    = (const float*)d_in[0];   // [T,B,I]
    const float* Win  = (const float*)d_in[1];   // [I,H]
    const float* Wrec = (const float*)d_in[2];   // [H,H]
    float* out = (float*)d_out;                  // [T,B,H] hiddens ++ [B,H] h_last

    dim3 g1(HID / 128, (T_STEPS * BATCH) / 128);
    xproj_gemm<<<g1, 256, 0, stream>>>(A, Win, out);
    rnn_scan<<<BATCH, 512, 0, stream>>>(Wrec, out);
}